// Round 1
// baseline (453.522 us; speedup 1.0000x reference)
//
#include <hip/hip_runtime.h>

#define N 512
#define ADJW (N/64)

__device__ __forceinline__ float limit_period_f(float v){
    const float TWO_PI_F = 6.2831853071795864769f;
    return v - floorf(v/TWO_PI_F + 0.5f)*TWO_PI_F;
}

__global__ void prep_kernel(const float* __restrict__ bin,
                            float* __restrict__ pre,
                            float* __restrict__ cor,
                            float* __restrict__ topv,
                            float* __restrict__ botv,
                            float* __restrict__ volv){
    int i = blockIdx.x*blockDim.x + threadIdx.x;
    if(i >= N) return;
    float b[7];
    #pragma unroll
    for(int d=0; d<7; ++d) b[d] = bin[i*7+d];
    float yaw = limit_period_f(b[6]);
    #pragma unroll
    for(int d=0; d<6; ++d) pre[i*7+d] = b[d];
    pre[i*7+6] = yaw;
    float c = cosf(yaw), s = sinf(yaw);
    const float tx[4] = {0.5f, 0.5f, -0.5f, -0.5f};
    const float ty[4] = {0.5f, -0.5f, -0.5f, 0.5f};
    #pragma unroll
    for(int k=0;k<4;++k){
        float px = tx[k]*b[5];   // x scaled by l = boxes[:,5]
        float py = ty[k]*b[4];   // y scaled by w = boxes[:,4]
        cor[i*8 + 2*k]   = px*c - py*s + b[0];
        cor[i*8 + 2*k+1] = px*s + py*c + b[1];
    }
    topv[i] = b[2] + b[3]*0.5f;
    botv[i] = b[2] - b[3]*0.5f;
    volv[i] = b[3]*b[4]*b[5];
}

// one thread per (i,j) pair; writes 1 bit (iou > 0.1) per pair via wave ballot
__global__ void iou_kernel(const float* __restrict__ cor,
                           const float* __restrict__ topv,
                           const float* __restrict__ botv,
                           const float* __restrict__ volv,
                           unsigned long long* __restrict__ adj){
    int i = blockIdx.x;
    int j = threadIdx.x;
    float axv[4], ayv[4], bxv[4], byv[4];
    #pragma unroll
    for(int k=0;k<4;++k){
        axv[k]=cor[i*8+2*k]; ayv[k]=cor[i*8+2*k+1];
        bxv[k]=cor[j*8+2*k]; byv[k]=cor[j*8+2*k+1];
    }
    float cx[24], cy[24], ang[24];
    unsigned vm = 0u;
    const float EPSQ = 1e-5f;
    // 16 edge-edge intersections (A edge e1 x B edge e2 -> index e1*4+e2)
    #pragma unroll
    for(int e1=0;e1<4;++e1){
        float a1x=axv[e1], a1y=ayv[e1];
        float d1x=axv[(e1+1)&3]-a1x, d1y=ayv[(e1+1)&3]-a1y;
        #pragma unroll
        for(int e2=0;e2<4;++e2){
            float b1x=bxv[e2], b1y=byv[e2];
            float d2x=bxv[(e2+1)&3]-b1x, d2y=byv[(e2+1)&3]-b1y;
            float den = d1x*d2y - d1y*d2x;
            bool okd = fabsf(den) > 1e-8f;
            float dens = okd ? den : 1e-8f;
            float wx = b1x-a1x, wy = b1y-a1y;
            float tt = (wx*d2y - wy*d2x)/dens;
            float uu = (wx*d1y - wy*d1x)/dens;
            bool ok = okd && (tt>=0.f) && (tt<=1.f) && (uu>=0.f) && (uu<=1.f);
            int k = e1*4+e2;
            cx[k] = a1x + tt*d1x;
            cy[k] = a1y + tt*d1y;
            if(ok) vm |= (1u<<k);
        }
    }
    // corners of A inside B  (cand idx 16..19)
    #pragma unroll
    for(int k=0;k<4;++k){
        float px=axv[k], py=ayv[k];
        bool le=true, ge=true;
        #pragma unroll
        for(int e=0;e<4;++e){
            float qx=bxv[e], qy=byv[e];
            float ux=bxv[(e+1)&3]-qx, uy=byv[(e+1)&3]-qy;
            float cc = ux*(py-qy) - uy*(px-qx);
            le = le && (cc <= EPSQ);
            ge = ge && (cc >= -EPSQ);
        }
        cx[16+k]=px; cy[16+k]=py;
        if(le||ge) vm |= (1u<<(16+k));
    }
    // corners of B inside A  (cand idx 20..23)
    #pragma unroll
    for(int k=0;k<4;++k){
        float px=bxv[k], py=byv[k];
        bool le=true, ge=true;
        #pragma unroll
        for(int e=0;e<4;++e){
            float qx=axv[e], qy=ayv[e];
            float ux=axv[(e+1)&3]-qx, uy=ayv[(e+1)&3]-qy;
            float cc = ux*(py-qy) - uy*(px-qx);
            le = le && (cc <= EPSQ);
            ge = ge && (cc >= -EPSQ);
        }
        cx[20+k]=px; cy[20+k]=py;
        if(le||ge) vm |= (1u<<(20+k));
    }
    // centroid of valid candidates (division, like the reference)
    float cntf = 0.f, sx=0.f, sy=0.f;
    #pragma unroll
    for(int k=0;k<24;++k){
        if((vm>>k)&1u){ cntf += 1.f; sx += cx[k]; sy += cy[k]; }
    }
    float denomc = fmaxf(cntf, 1.f);
    float cenx = sx/denomc, ceny = sy/denomc;
    #pragma unroll
    for(int k=0;k<24;++k){
        ang[k] = ((vm>>k)&1u) ? atan2f(cy[k]-ceny, cx[k]-cenx) : 1e9f;
    }
    // stable selection by (angle, original index), shoelace in sorted order
    int cN = __popc(vm);
    unsigned used = ~vm;
    float fx=0.f, fy=0.f, pxp=0.f, pyp=0.f, acc=0.f;
    for(int k=0;k<cN;++k){
        float best = 1e30f; float bx2=0.f, by2=0.f; int bi=0;
        #pragma unroll
        for(int t=0;t<24;++t){
            bool better = (((used>>t)&1u)==0u) && (ang[t] < best);
            if(better){ best=ang[t]; bx2=cx[t]-cenx; by2=cy[t]-ceny; bi=t; }
        }
        used |= (1u<<bi);
        if(k==0){ fx=bx2; fy=by2; }
        else { acc += pxp*by2 - pyp*bx2; }
        pxp=bx2; pyp=by2;
    }
    acc += pxp*fy - pyp*fx;   // wrap term (invalid slots duplicate first point -> zero)
    float area = 0.5f*fabsf(acc);
    float inter_bev = (cntf >= 3.f) ? area : 0.f;
    float oh = fmaxf(fminf(topv[i], topv[j]) - fmaxf(botv[i], botv[j]), 0.f);
    float inter = inter_bev * oh;
    float iou = inter / fmaxf(volv[i]+volv[j]-inter, 1e-6f);
    bool pred = iou > 0.1f;
    unsigned long long m = __ballot(pred);
    if((j & 63) == 0) adj[i*ADJW + (j>>6)] = m;
}

// sequential greedy clustering, replicating the reference's overwrite semantics
__global__ void cluster_kernel(const unsigned long long* __restrict__ adj,
                               int* __restrict__ ci_out){
    __shared__ int firstIdx;
    int t = threadIdx.x;
    int myci = 0;
    int cid = 1;
    for(;;){
        if(t==0) firstIdx = N;
        __syncthreads();
        if(myci == 0) atomicMin(&firstIdx, t);
        __syncthreads();
        int idx = firstIdx;
        if(idx >= N) break;
        bool hit = (adj[idx*ADJW + (t>>6)] >> (unsigned)(t&63)) & 1ull;
        if(hit) myci = cid;     // unconditional overwrite, like jnp.where
        cid++;
        __syncthreads();        // protect firstIdx reset of next iteration
    }
    ci_out[t] = myci;
}

// thread t owns box t AND segment s=t+1; all scans in ascending index order
__global__ void fuse_kernel(const float* __restrict__ pre,
                            const float* __restrict__ scores,
                            const int* __restrict__ ci,
                            const int* __restrict__ fhp,
                            const int* __restrict__ fwp,
                            float* __restrict__ out){
    const float PI_F      = 3.14159265358979323846f;
    const float HALF_PI_F = 1.57079632679489662f;
    const float TWO_PI_F  = 6.2831853071795864769f;
    int t = threadIdx.x;
    __shared__ float s_sc[N], s_dir[N], s_smax[N], s_ssum[N], s_dref[N], s_dir2[N], s_sn[N];
    __shared__ int s_ci[N];
    __shared__ unsigned char s_keep[N];
    s_sc[t]  = scores[t];
    s_dir[t] = pre[t*7+6];
    s_ci[t]  = ci[t];
    __syncthreads();
    int s = t + 1;
    // per-segment: count, max score, score sum
    float cnt = 0.f, smax = -1e30f, ssum = 0.f;
    for(int i=0;i<N;++i){
        if(s_ci[i]==s){ cnt += 1.f; smax = fmaxf(smax, s_sc[i]); ssum += s_sc[i]; }
    }
    // per-segment: dref = max over members of (is_max ? dir : -1e9)
    float dref = -1e9f;
    for(int i=0;i<N;++i){
        if(s_ci[i]==s){
            float v = (s_sc[i]==smax) ? s_dir[i] : -1e9f;
            dref = fmaxf(dref, v);
        }
    }
    // per-segment: score mass of gt vs not-gt
    float slt = 0.f, sle = 0.f;
    for(int i=0;i<N;++i){
        if(s_ci[i]==s){
            float diff = fabsf(s_dir[i] - dref);
            diff = (diff > PI_F) ? (TWO_PI_F - diff) : diff;
            if(diff > HALF_PI_F) slt += s_sc[i]; else sle += s_sc[i];
        }
    }
    s_smax[t]=smax; s_ssum[t]=ssum; s_dref[t]=dref;
    s_keep[t] = (slt <= sle) ? 1 : 0;
    __syncthreads();
    // per-box: flip decision, flipped dir, normalized score
    {
        int seg = s_ci[t];          // clustering guarantees seg >= 1
        float drefb = s_dref[seg-1];
        float diff = fabsf(s_dir[t] - drefb);
        diff = (diff > PI_F) ? (TWO_PI_F - diff) : diff;
        bool gt = diff > HALF_PI_F;
        bool keep = s_keep[seg-1] != 0;
        bool flip = keep ? gt : !gt;
        float d2 = s_dir[t] + (flip ? PI_F : 0.f);
        s_dir2[t] = limit_period_f(d2);
        s_sn[t] = s_sc[t] / s_ssum[seg-1];
    }
    __syncthreads();
    // per-segment: weighted sums
    float ssin=0.f, scos=0.f;
    float cd[6] = {0.f,0.f,0.f,0.f,0.f,0.f};
    for(int i=0;i<N;++i){
        if(s_ci[i]==s){
            float sn = s_sn[i];
            ssin += sinf(s_dir2[i])*sn;
            scos += cosf(s_dir2[i])*sn;
            #pragma unroll
            for(int d=0;d<6;++d) cd[d] += pre[i*7+d]*sn;
        }
    }
    float theta = atan2f(ssin, scos);
    bool valid = cnt > 0.f;
    float bf[7];
    #pragma unroll
    for(int d=0;d<6;++d) bf[d] = valid ? cd[d] : 0.f;
    bf[6] = valid ? theta : 0.f;
    // range mask on (already zeroed-if-invalid) fused box, as the reference does
    {
        float cth=cosf(bf[6]), sth=sinf(bf[6]);
        const float tx[4]={0.5f,0.5f,-0.5f,-0.5f};
        const float ty[4]={0.5f,-0.5f,-0.5f,0.5f};
        bool inb = true;
        #pragma unroll
        for(int k=0;k<4;++k){
            float pxl = tx[k]*bf[5], pyl = ty[k]*bf[4];
            float gx = pxl*cth - pyl*sth + bf[0];
            float gy = pxl*sth + pyl*cth + bf[1];
            inb = inb && (gx > -140.8f) && (gx < 140.8f) && (gy > -40.0f) && (gy < 40.0f);
        }
        valid = valid && inb;
    }
    if(!valid){
        #pragma unroll
        for(int d=0;d<7;++d) bf[d]=0.f;
    }
    float sf = valid ? smax : 0.f;
    // roi
    int fh = *fhp, fw = *fwp;
    float ghf = (float)((40.0 - (-40.0)) / (double)fh);
    float gwf = (float)((140.8 - (-140.8)) / (double)fw);
    float gcx = (bf[0] + 140.8f) / gwf;
    float gcy = (bf[1] + 40.0f) / ghf;
    float gox = bf[5]*0.5f / gwf;
    float goy = bf[4]*0.5f / ghf + 1.0f;
    float xmin = fmaxf(gcx - gox, 0.f);
    float xmax = fminf(gcx + gox, (float)fw - 1.0f);
    float ymin = fmaxf(gcy - goy, 0.f);
    float ymax = fminf(gcy + goy, (float)fh - 1.0f);
    int r0 = (int)xmin, r1 = (int)xmax, r2 = (int)ymin, r3 = (int)ymax;
    if(!valid){ r0=0; r1=0; r2=0; r3=0; }
    #pragma unroll
    for(int d=0;d<7;++d) out[t*7+d] = bf[d];
    out[N*7 + t] = sf;                       // scores_f
    out[N*8 + t] = valid ? 1.f : 0.f;        // valid
    out[N*9 + t*4 + 0] = (float)r0;          // roi
    out[N*9 + t*4 + 1] = (float)r1;
    out[N*9 + t*4 + 2] = (float)r2;
    out[N*9 + t*4 + 3] = (float)r3;
}

extern "C" void kernel_launch(void* const* d_in, const int* in_sizes, int n_in,
                              void* d_out, int out_size, void* d_ws, size_t ws_size,
                              hipStream_t stream) {
    const float* boxes  = (const float*)d_in[0];
    const float* scores = (const float*)d_in[1];
    const int*   fhp    = (const int*)d_in[2];
    const int*   fwp    = (const int*)d_in[3];
    float* out = (float*)d_out;
    char* ws = (char*)d_ws;
    // ws layout (bytes):
    float* pre  = (float*)(ws + 0);        // 512*7*4 = 14336
    float* cor  = (float*)(ws + 14336);    // 512*8*4 = 16384 -> 30720
    float* topv = (float*)(ws + 30720);    // 2048 -> 32768
    float* botv = (float*)(ws + 32768);    // 2048 -> 34816
    float* volv = (float*)(ws + 34816);    // 2048 -> 36864
    unsigned long long* adj = (unsigned long long*)(ws + 36864); // 512*8*8 = 32768 -> 69632
    int* ci = (int*)(ws + 69632);          // 2048 -> 71680 total

    prep_kernel<<<2, 256, 0, stream>>>(boxes, pre, cor, topv, botv, volv);
    iou_kernel<<<N, 512, 0, stream>>>(cor, topv, botv, volv, adj);
    cluster_kernel<<<1, 512, 0, stream>>>(adj, ci);
    fuse_kernel<<<1, 512, 0, stream>>>(pre, scores, ci, fhp, fwp, out);
}

// Round 2
// 123.284 us; speedup vs baseline: 3.6787x; 3.6787x over previous
//
#include <hip/hip_runtime.h>

#define N 512
#define ADJW (N/64)
typedef unsigned long long ull;

__device__ __forceinline__ float limit_period_f(float v){
    const float TWO_PI_F = 6.2831853071795864769f;
    return v - floorf(v/TWO_PI_F + 0.5f)*TWO_PI_F;
}

// one thread per (i,j) pair; writes 1 bit (iou > 0.1) per pair via wave ballot
__global__ __launch_bounds__(512) void iou_kernel(const float* __restrict__ boxes,
                                                  ull* __restrict__ adj){
    int i = blockIdx.x;
    int j = threadIdx.x;
    float bi0=boxes[i*7+0], bi1=boxes[i*7+1], bi2=boxes[i*7+2], bi3=boxes[i*7+3],
          bi4=boxes[i*7+4], bi5=boxes[i*7+5], bi6=boxes[i*7+6];
    float bj0=boxes[j*7+0], bj1=boxes[j*7+1], bj2=boxes[j*7+2], bj3=boxes[j*7+3],
          bj4=boxes[j*7+4], bj5=boxes[j*7+5], bj6=boxes[j*7+6];

    float topi = bi2 + bi3*0.5f, boti = bi2 - bi3*0.5f, voli = bi3*bi4*bi5;
    float topj = bj2 + bj3*0.5f, botj = bj2 - bj3*0.5f, volj = bj3*bj4*bj5;
    float oh = fminf(topi, topj) - fmaxf(boti, botj);

    // conservative early reject: BEV circumcircles disjoint or z-extents disjoint => iou == 0
    float dx = bi0 - bj0, dy = bi1 - bj1;
    float ra = 0.5f*sqrtf(bi5*bi5 + bi4*bi4);
    float rb = 0.5f*sqrtf(bj5*bj5 + bj4*bj4);
    float rr = ra + rb + 0.01f;
    bool pred = false;

    if(dx*dx + dy*dy <= rr*rr && oh > 0.0f){
        // corners (limited yaw, matching reference)
        const float tx[4] = {0.5f, 0.5f, -0.5f, -0.5f};
        const float ty[4] = {0.5f, -0.5f, -0.5f, 0.5f};
        float yawi = limit_period_f(bi6);
        float yawj = limit_period_f(bj6);
        float cA = cosf(yawi), sA = sinf(yawi);
        float cB = cosf(yawj), sB = sinf(yawj);
        float axv[4], ayv[4], bxv[4], byv[4];
        #pragma unroll
        for(int k=0;k<4;++k){
            float px = tx[k]*bi5, py = ty[k]*bi4;
            axv[k] = px*cA - py*sA + bi0;
            ayv[k] = px*sA + py*cA + bi1;
            float qx = tx[k]*bj5, qy = ty[k]*bj4;
            bxv[k] = qx*cB - qy*sB + bj0;
            byv[k] = qx*sB + qy*cB + bj1;
        }
        float cx[24], cy[24], ang[24];
        unsigned vm = 0u;
        const float EPSQ = 1e-5f;
        // 16 edge-edge intersections (A edge e1 x B edge e2 -> index e1*4+e2)
        #pragma unroll
        for(int e1=0;e1<4;++e1){
            float a1x=axv[e1], a1y=ayv[e1];
            float d1x=axv[(e1+1)&3]-a1x, d1y=ayv[(e1+1)&3]-a1y;
            #pragma unroll
            for(int e2=0;e2<4;++e2){
                float b1x=bxv[e2], b1y=byv[e2];
                float d2x=bxv[(e2+1)&3]-b1x, d2y=byv[(e2+1)&3]-b1y;
                float den = d1x*d2y - d1y*d2x;
                bool okd = fabsf(den) > 1e-8f;
                float dens = okd ? den : 1e-8f;
                float wx = b1x-a1x, wy = b1y-a1y;
                float tt = (wx*d2y - wy*d2x)/dens;
                float uu = (wx*d1y - wy*d1x)/dens;
                bool ok = okd && (tt>=0.f) && (tt<=1.f) && (uu>=0.f) && (uu<=1.f);
                int k = e1*4+e2;
                cx[k] = a1x + tt*d1x;
                cy[k] = a1y + tt*d1y;
                if(ok) vm |= (1u<<k);
            }
        }
        // corners of A inside B (16..19)
        #pragma unroll
        for(int k=0;k<4;++k){
            float px=axv[k], py=ayv[k];
            bool le=true, ge=true;
            #pragma unroll
            for(int e=0;e<4;++e){
                float qx=bxv[e], qy=byv[e];
                float ux=bxv[(e+1)&3]-qx, uy=byv[(e+1)&3]-qy;
                float cc = ux*(py-qy) - uy*(px-qx);
                le = le && (cc <= EPSQ);
                ge = ge && (cc >= -EPSQ);
            }
            cx[16+k]=px; cy[16+k]=py;
            if(le||ge) vm |= (1u<<(16+k));
        }
        // corners of B inside A (20..23)
        #pragma unroll
        for(int k=0;k<4;++k){
            float px=bxv[k], py=byv[k];
            bool le=true, ge=true;
            #pragma unroll
            for(int e=0;e<4;++e){
                float qx=axv[e], qy=ayv[e];
                float ux=axv[(e+1)&3]-qx, uy=ayv[(e+1)&3]-qy;
                float cc = ux*(py-qy) - uy*(px-qx);
                le = le && (cc <= EPSQ);
                ge = ge && (cc >= -EPSQ);
            }
            cx[20+k]=px; cy[20+k]=py;
            if(le||ge) vm |= (1u<<(20+k));
        }
        // centroid of valid candidates
        float cntf = 0.f, sx=0.f, sy=0.f;
        #pragma unroll
        for(int k=0;k<24;++k){
            if((vm>>k)&1u){ cntf += 1.f; sx += cx[k]; sy += cy[k]; }
        }
        float denomc = fmaxf(cntf, 1.f);
        float cenx = sx/denomc, ceny = sy/denomc;
        #pragma unroll
        for(int k=0;k<24;++k){
            ang[k] = ((vm>>k)&1u) ? atan2f(cy[k]-ceny, cx[k]-cenx) : 1e9f;
        }
        // stable selection by (angle, original index), shoelace in sorted order
        int cN = __popc(vm);
        unsigned used = ~vm;
        float fx=0.f, fy=0.f, pxp=0.f, pyp=0.f, acc=0.f;
        for(int k=0;k<cN;++k){
            float best = 1e30f; float bx2=0.f, by2=0.f; int bi=0;
            #pragma unroll
            for(int t2=0;t2<24;++t2){
                bool better = (((used>>t2)&1u)==0u) && (ang[t2] < best);
                if(better){ best=ang[t2]; bx2=cx[t2]-cenx; by2=cy[t2]-ceny; bi=t2; }
            }
            used |= (1u<<bi);
            if(k==0){ fx=bx2; fy=by2; }
            else { acc += pxp*by2 - pyp*bx2; }
            pxp=bx2; pyp=by2;
        }
        acc += pxp*fy - pyp*fx;
        float area = 0.5f*fabsf(acc);
        float inter_bev = (cntf >= 3.f) ? area : 0.f;
        float inter = inter_bev * oh;      // oh > 0 in this branch
        float iou = inter / fmaxf(voli+volj-inter, 1e-6f);
        pred = iou > 0.1f;
    }
    ull m = __ballot(pred);
    if((j & 63) == 0) adj[i*ADJW + (j>>6)] = m;
}

// single block: clustering (wave 0) + CSR-based cluster fusion + outputs
__global__ __launch_bounds__(512) void cluster_fuse_kernel(
        const float* __restrict__ boxes,
        const float* __restrict__ scores,
        const ull* __restrict__ adj,
        const int* __restrict__ fhp,
        const int* __restrict__ fwp,
        float* __restrict__ out){
    const float PI_F      = 3.14159265358979323846f;
    const float HALF_PI_F = 1.57079632679489662f;
    const float TWO_PI_F  = 6.2831853071795864769f;
    int t = threadIdx.x;

    __shared__ ull   s_adj[N*ADJW];   // 32 KB
    __shared__ float s_sc[N], s_dir[N];
    __shared__ int   s_ci[N];
    __shared__ int   s_off[N];
    __shared__ int   s_mem[N];
    __shared__ float s_dref[N], s_ssum[N];
    __shared__ float s_val[8][N];
    __shared__ unsigned char s_keep[N];

    // load per-box data
    float b0=boxes[t*7+0], b1=boxes[t*7+1], b2=boxes[t*7+2], b3=boxes[t*7+3],
          b4=boxes[t*7+4], b5=boxes[t*7+5], b6=boxes[t*7+6];
    float dir = limit_period_f(b6);
    float sc  = scores[t];
    s_sc[t] = sc;
    s_dir[t] = dir;
    #pragma unroll
    for(int k=0;k<ADJW;++k) s_adj[k*N + t] = adj[k*N + t];
    __syncthreads();

    // ---- clustering: wave 0 only, lane L owns boxes L*8..L*8+7 ----
    if(t < 64){
        int mc[8];
        #pragma unroll
        for(int k=0;k<8;++k) mc[k] = 0;
        unsigned myset = 0u;
        int cid = 1;
        const unsigned char* ab = (const unsigned char*)s_adj;
        for(;;){
            ull un = __ballot((myset & 0xFFu) != 0xFFu);
            if(un == 0ull) break;
            int lane = (int)__ffsll(un) - 1;
            unsigned ms = (unsigned)__shfl((int)myset, lane);
            int sub = __ffs((int)(~ms & 0xFFu)) - 1;
            int idx = lane*8 + sub;
            unsigned v = (unsigned)ab[idx*64 + t];
            #pragma unroll
            for(int k=0;k<8;++k){
                if((v>>k)&1u) mc[k] = cid;
            }
            myset |= v;
            cid++;
        }
        #pragma unroll
        for(int k=0;k<8;++k) s_ci[t*8+k] = mc[k];
    }
    __syncthreads();

    // ---- combined scan: per-segment count/smax/ssum + per-box rank ----
    int myci = s_ci[t];
    int s = t + 1;                       // thread t owns segment t+1
    int icnt = 0, rank = 0;
    float smax = -1e30f, ssum = 0.f;
    for(int i=0;i<N;++i){
        int ci_i  = s_ci[i];
        float sci = s_sc[i];
        if(ci_i == s){ icnt++; smax = fmaxf(smax, sci); ssum += sci; }
        if(i < t && ci_i == myci) rank++;
    }

    // ---- exclusive prefix sum of counts (Hillis-Steele) ----
    s_off[t] = icnt;
    __syncthreads();
    #pragma unroll
    for(int d=1; d<N; d<<=1){
        int v = (t >= d) ? s_off[t-d] : 0;
        __syncthreads();
        s_off[t] += v;
        __syncthreads();
    }
    int incl = s_off[t];
    __syncthreads();
    s_off[t] = incl - icnt;              // exclusive offset for segment t+1
    __syncthreads();

    // ---- scatter member list (ascending index order preserved via rank) ----
    s_mem[s_off[myci-1] + rank] = t;
    __syncthreads();

    // ---- per-segment: dref then slt/sle (member loops, same owner) ----
    int base = s_off[t];
    float dref = -1e9f;
    for(int k=0;k<icnt;++k){
        int i = s_mem[base+k];
        float v = (s_sc[i] == smax) ? s_dir[i] : -1e9f;
        dref = fmaxf(dref, v);
    }
    float slt = 0.f, sle = 0.f;
    for(int k=0;k<icnt;++k){
        int i = s_mem[base+k];
        float diff = fabsf(s_dir[i] - dref);
        diff = (diff > PI_F) ? (TWO_PI_F - diff) : diff;
        if(diff > HALF_PI_F) slt += s_sc[i]; else sle += s_sc[i];
    }
    s_dref[t] = dref;
    s_ssum[t] = ssum;
    s_keep[t] = (slt <= sle) ? 1 : 0;
    __syncthreads();

    // ---- per-box: flip, dir2, sn, weighted values (trig once per box) ----
    {
        int ow = myci - 1;
        float drefb = s_dref[ow];
        float diff = fabsf(dir - drefb);
        diff = (diff > PI_F) ? (TWO_PI_F - diff) : diff;
        bool gt = diff > HALF_PI_F;
        bool keep = s_keep[ow] != 0;
        bool flip = keep ? gt : !gt;
        float d2 = limit_period_f(dir + (flip ? PI_F : 0.f));
        float sn = sc / s_ssum[ow];
        s_val[0][t] = sinf(d2)*sn;
        s_val[1][t] = cosf(d2)*sn;
        s_val[2][t] = b0*sn;
        s_val[3][t] = b1*sn;
        s_val[4][t] = b2*sn;
        s_val[5][t] = b3*sn;
        s_val[6][t] = b4*sn;
        s_val[7][t] = b5*sn;
    }
    __syncthreads();

    // ---- per-segment weighted sums (ascending member order) ----
    float ssin=0.f, scos=0.f;
    float cd[6] = {0.f,0.f,0.f,0.f,0.f,0.f};
    for(int k=0;k<icnt;++k){
        int i = s_mem[base+k];
        ssin  += s_val[0][i];
        scos  += s_val[1][i];
        cd[0] += s_val[2][i];
        cd[1] += s_val[3][i];
        cd[2] += s_val[4][i];
        cd[3] += s_val[5][i];
        cd[4] += s_val[6][i];
        cd[5] += s_val[7][i];
    }
    float theta = atan2f(ssin, scos);

    // ---- epilogue (identical to round-1 passing code) ----
    bool valid = icnt > 0;
    float bf[7];
    #pragma unroll
    for(int d=0;d<6;++d) bf[d] = valid ? cd[d] : 0.f;
    bf[6] = valid ? theta : 0.f;
    {
        float cth=cosf(bf[6]), sth=sinf(bf[6]);
        const float tx[4]={0.5f,0.5f,-0.5f,-0.5f};
        const float ty[4]={0.5f,-0.5f,-0.5f,0.5f};
        bool inb = true;
        #pragma unroll
        for(int k=0;k<4;++k){
            float pxl = tx[k]*bf[5], pyl = ty[k]*bf[4];
            float gx = pxl*cth - pyl*sth + bf[0];
            float gy = pxl*sth + pyl*cth + bf[1];
            inb = inb && (gx > -140.8f) && (gx < 140.8f) && (gy > -40.0f) && (gy < 40.0f);
        }
        valid = valid && inb;
    }
    if(!valid){
        #pragma unroll
        for(int d=0;d<7;++d) bf[d]=0.f;
    }
    float sf = valid ? smax : 0.f;
    int fh = *fhp, fw = *fwp;
    float ghf = (float)((40.0 - (-40.0)) / (double)fh);
    float gwf = (float)((140.8 - (-140.8)) / (double)fw);
    float gcx = (bf[0] + 140.8f) / gwf;
    float gcy = (bf[1] + 40.0f) / ghf;
    float gox = bf[5]*0.5f / gwf;
    float goy = bf[4]*0.5f / ghf + 1.0f;
    float xmin = fmaxf(gcx - gox, 0.f);
    float xmax = fminf(gcx + gox, (float)fw - 1.0f);
    float ymin = fmaxf(gcy - goy, 0.f);
    float ymax = fminf(gcy + goy, (float)fh - 1.0f);
    int r0 = (int)xmin, r1 = (int)xmax, r2 = (int)ymin, r3 = (int)ymax;
    if(!valid){ r0=0; r1=0; r2=0; r3=0; }
    #pragma unroll
    for(int d=0;d<7;++d) out[t*7+d] = bf[d];
    out[N*7 + t] = sf;
    out[N*8 + t] = valid ? 1.f : 0.f;
    out[N*9 + t*4 + 0] = (float)r0;
    out[N*9 + t*4 + 1] = (float)r1;
    out[N*9 + t*4 + 2] = (float)r2;
    out[N*9 + t*4 + 3] = (float)r3;
}

extern "C" void kernel_launch(void* const* d_in, const int* in_sizes, int n_in,
                              void* d_out, int out_size, void* d_ws, size_t ws_size,
                              hipStream_t stream) {
    const float* boxes  = (const float*)d_in[0];
    const float* scores = (const float*)d_in[1];
    const int*   fhp    = (const int*)d_in[2];
    const int*   fwp    = (const int*)d_in[3];
    float* out = (float*)d_out;
    ull* adj = (ull*)d_ws;               // 512*8*8 = 32768 bytes

    iou_kernel<<<N, 512, 0, stream>>>(boxes, adj);
    cluster_fuse_kernel<<<1, 512, 0, stream>>>(boxes, scores, adj, fhp, fwp, out);
}

// Round 3
// 73.566 us; speedup vs baseline: 6.1648x; 1.6758x over previous
//
#include <hip/hip_runtime.h>

#define N 512
#define ADJW (N/64)
typedef unsigned long long ull;

__device__ __forceinline__ float limit_period_f(float v){
    const float TWO_PI_F = 6.2831853071795864769f;
    return v - floorf(v/TWO_PI_F + 0.5f)*TWO_PI_F;
}

// Block i owns row i. Phase 1: all 512 threads cheap-reject their j.
// Phase 2: compact candidates to LDS; threads t<C run full geometry.
__global__ __launch_bounds__(512) void iou_kernel(const float* __restrict__ boxes,
                                                  ull* __restrict__ adj){
    int i = blockIdx.x;
    int t = threadIdx.x;
    int lane = t & 63, w = t >> 6;
    __shared__ float s_bi[7];
    __shared__ int   s_wcnt[8];
    __shared__ int   s_list[N];
    __shared__ ull   s_row[ADJW];
    if(t < 7) s_bi[t] = boxes[i*7+t];
    if(t < ADJW) s_row[t] = 0ull;
    __syncthreads();
    float bi0=s_bi[0], bi1=s_bi[1], bi2=s_bi[2], bi3=s_bi[3],
          bi4=s_bi[4], bi5=s_bi[5], bi6=s_bi[6];

    // ---- phase 1: cheap conservative reject for j = t ----
    int j = t;
    float bj0=boxes[j*7+0], bj1=boxes[j*7+1], bj2=boxes[j*7+2], bj3=boxes[j*7+3],
          bj4=boxes[j*7+4], bj5=boxes[j*7+5];
    float topi = bi2 + bi3*0.5f, boti = bi2 - bi3*0.5f;
    float topj = bj2 + bj3*0.5f, botj = bj2 - bj3*0.5f;
    float oh = fminf(topi, topj) - fmaxf(boti, botj);
    float dx = bi0 - bj0, dy = bi1 - bj1;
    float ra = 0.5f*sqrtf(bi5*bi5 + bi4*bi4);
    float rb = 0.5f*sqrtf(bj5*bj5 + bj4*bj4);
    float rr = ra + rb + 0.01f;
    bool cand = (dx*dx + dy*dy <= rr*rr) && (oh > 0.0f);

    ull m = __ballot(cand);
    if(lane == 0) s_wcnt[w] = __popcll(m);
    int prefix = __popcll(m & ((1ull<<lane) - 1ull));
    __syncthreads();
    int base = 0, C = 0;
    #pragma unroll
    for(int k=0;k<8;++k){ int c = s_wcnt[k]; if(k < w) base += c; C += c; }
    if(cand) s_list[base + prefix] = j;
    __syncthreads();

    // ---- phase 2: full geometry on compacted candidates ----
    if(t < C){
        int jj = s_list[t];
        float cj0=boxes[jj*7+0], cj1=boxes[jj*7+1], cj2=boxes[jj*7+2], cj3=boxes[jj*7+3],
              cj4=boxes[jj*7+4], cj5=boxes[jj*7+5], cj6=boxes[jj*7+6];
        float voli = bi3*bi4*bi5;
        float volj = cj3*cj4*cj5;
        float topj2 = cj2 + cj3*0.5f, botj2 = cj2 - cj3*0.5f;
        float oh2 = fminf(topi, topj2) - fmaxf(boti, botj2);   // > 0 for candidates

        const float tx[4] = {0.5f, 0.5f, -0.5f, -0.5f};
        const float ty[4] = {0.5f, -0.5f, -0.5f, 0.5f};
        float yawi = limit_period_f(bi6);
        float yawj = limit_period_f(cj6);
        float cA = cosf(yawi), sA = sinf(yawi);
        float cB = cosf(yawj), sB = sinf(yawj);
        float axv[4], ayv[4], bxv[4], byv[4];
        #pragma unroll
        for(int k=0;k<4;++k){
            float px = tx[k]*bi5, py = ty[k]*bi4;
            axv[k] = px*cA - py*sA + bi0;
            ayv[k] = px*sA + py*cA + bi1;
            float qx = tx[k]*cj5, qy = ty[k]*cj4;
            bxv[k] = qx*cB - qy*sB + cj0;
            byv[k] = qx*sB + qy*cB + cj1;
        }
        float cx[24], cy[24], ang[24];
        unsigned vm = 0u;
        const float EPSQ = 1e-5f;
        #pragma unroll
        for(int e1=0;e1<4;++e1){
            float a1x=axv[e1], a1y=ayv[e1];
            float d1x=axv[(e1+1)&3]-a1x, d1y=ayv[(e1+1)&3]-a1y;
            #pragma unroll
            for(int e2=0;e2<4;++e2){
                float b1x=bxv[e2], b1y=byv[e2];
                float d2x=bxv[(e2+1)&3]-b1x, d2y=byv[(e2+1)&3]-b1y;
                float den = d1x*d2y - d1y*d2x;
                bool okd = fabsf(den) > 1e-8f;
                float dens = okd ? den : 1e-8f;
                float wx = b1x-a1x, wy = b1y-a1y;
                float tt = (wx*d2y - wy*d2x)/dens;
                float uu = (wx*d1y - wy*d1x)/dens;
                bool ok = okd && (tt>=0.f) && (tt<=1.f) && (uu>=0.f) && (uu<=1.f);
                int k = e1*4+e2;
                cx[k] = a1x + tt*d1x;
                cy[k] = a1y + tt*d1y;
                if(ok) vm |= (1u<<k);
            }
        }
        #pragma unroll
        for(int k=0;k<4;++k){
            float px=axv[k], py=ayv[k];
            bool le=true, ge=true;
            #pragma unroll
            for(int e=0;e<4;++e){
                float qx=bxv[e], qy=byv[e];
                float ux=bxv[(e+1)&3]-qx, uy=byv[(e+1)&3]-qy;
                float cc = ux*(py-qy) - uy*(px-qx);
                le = le && (cc <= EPSQ);
                ge = ge && (cc >= -EPSQ);
            }
            cx[16+k]=px; cy[16+k]=py;
            if(le||ge) vm |= (1u<<(16+k));
        }
        #pragma unroll
        for(int k=0;k<4;++k){
            float px=bxv[k], py=byv[k];
            bool le=true, ge=true;
            #pragma unroll
            for(int e=0;e<4;++e){
                float qx=axv[e], qy=ayv[e];
                float ux=axv[(e+1)&3]-qx, uy=ayv[(e+1)&3]-qy;
                float cc = ux*(py-qy) - uy*(px-qx);
                le = le && (cc <= EPSQ);
                ge = ge && (cc >= -EPSQ);
            }
            cx[20+k]=px; cy[20+k]=py;
            if(le||ge) vm |= (1u<<(20+k));
        }
        float cntf = 0.f, sx=0.f, sy=0.f;
        #pragma unroll
        for(int k=0;k<24;++k){
            if((vm>>k)&1u){ cntf += 1.f; sx += cx[k]; sy += cy[k]; }
        }
        float denomc = fmaxf(cntf, 1.f);
        float cenx = sx/denomc, ceny = sy/denomc;
        #pragma unroll
        for(int k=0;k<24;++k){
            ang[k] = ((vm>>k)&1u) ? atan2f(cy[k]-ceny, cx[k]-cenx) : 1e9f;
        }
        int cN = __popc(vm);
        unsigned used = ~vm;
        float fx=0.f, fy=0.f, pxp=0.f, pyp=0.f, acc=0.f;
        for(int k=0;k<cN;++k){
            float best = 1e30f; float bx2=0.f, by2=0.f; int bsel=0;
            #pragma unroll
            for(int t2=0;t2<24;++t2){
                bool better = (((used>>t2)&1u)==0u) && (ang[t2] < best);
                if(better){ best=ang[t2]; bx2=cx[t2]-cenx; by2=cy[t2]-ceny; bsel=t2; }
            }
            used |= (1u<<bsel);
            if(k==0){ fx=bx2; fy=by2; }
            else { acc += pxp*by2 - pyp*bx2; }
            pxp=bx2; pyp=by2;
        }
        acc += pxp*fy - pyp*fx;
        float area = 0.5f*fabsf(acc);
        float inter_bev = (cntf >= 3.f) ? area : 0.f;
        float inter = inter_bev * oh2;
        float iou = inter / fmaxf(voli+volj-inter, 1e-6f);
        if(iou > 0.1f) atomicOr(&s_row[jj>>6], 1ull<<(jj&63));
    }
    __syncthreads();
    if(t < ADJW) adj[i*ADJW + t] = s_row[t];
}

// single block: clustering (wave 0) + CSR member lists + fusion + outputs
__global__ __launch_bounds__(512) void cluster_fuse_kernel(
        const float* __restrict__ boxes,
        const float* __restrict__ scores,
        const ull* __restrict__ adj,
        const int* __restrict__ fhp,
        const int* __restrict__ fwp,
        float* __restrict__ out){
    const float PI_F      = 3.14159265358979323846f;
    const float HALF_PI_F = 1.57079632679489662f;
    const float TWO_PI_F  = 6.2831853071795864769f;
    int t = threadIdx.x;
    int lane = t & 63, w = t >> 6;

    __shared__ ull   s_adj[N*ADJW];   // 32 KB
    __shared__ float s_sc[N], s_dir[N];
    __shared__ int   s_ci[N];
    __shared__ int   s_cnt[N], s_off[N], s_pos[N], s_mem[N];
    __shared__ float s_dref[N], s_ssum[N], s_smax[N];
    __shared__ float s_val[8][N];
    __shared__ unsigned char s_keep[N];
    __shared__ int   s_wsum[8];

    float b0=boxes[t*7+0], b1=boxes[t*7+1], b2=boxes[t*7+2], b3=boxes[t*7+3],
          b4=boxes[t*7+4], b5=boxes[t*7+5], b6=boxes[t*7+6];
    float dir = limit_period_f(b6);
    float sc  = scores[t];
    s_sc[t] = sc;
    s_dir[t] = dir;
    s_cnt[t] = 0;
    #pragma unroll
    for(int k=0;k<ADJW;++k) s_adj[k*N + t] = adj[k*N + t];
    __syncthreads();

    // ---- clustering: wave 0 only, lane L owns boxes L*8..L*8+7 ----
    if(t < 64){
        int mc[8];
        #pragma unroll
        for(int k=0;k<8;++k) mc[k] = 0;
        unsigned myset = 0u;
        int cid = 1;
        const unsigned char* ab = (const unsigned char*)s_adj;
        for(;;){
            ull un = __ballot((myset & 0xFFu) != 0xFFu);
            if(un == 0ull) break;
            int ln = (int)__ffsll(un) - 1;
            unsigned ms = (unsigned)__shfl((int)myset, ln);
            int sub = __ffs((int)(~ms & 0xFFu)) - 1;
            int idx = ln*8 + sub;
            unsigned v = (unsigned)ab[idx*64 + t];
            #pragma unroll
            for(int k=0;k<8;++k){
                if((v>>k)&1u) mc[k] = cid;
            }
            myset |= v;
            cid++;
        }
        #pragma unroll
        for(int k=0;k<8;++k) s_ci[t*8+k] = mc[k];
    }
    __syncthreads();

    // ---- per-segment counts via LDS atomics ----
    int myci = s_ci[t];
    atomicAdd(&s_cnt[myci-1], 1);
    __syncthreads();
    int icnt = s_cnt[t];            // thread t owns segment t+1

    // ---- exclusive prefix sum: shfl wave-scan + cross-wave fixup ----
    int v = icnt;
    #pragma unroll
    for(int d=1; d<64; d<<=1){
        int u = __shfl_up(v, d);
        if(lane >= d) v += u;
    }
    if(lane == 63) s_wsum[w] = v;
    __syncthreads();
    int woff = 0;
    #pragma unroll
    for(int k=0;k<8;++k){ if(k < w) woff += s_wsum[k]; }
    int excl = woff + v - icnt;
    s_off[t] = excl;
    s_pos[t] = excl;
    __syncthreads();

    // ---- scatter members (unordered), then owner sorts ascending ----
    int r = atomicAdd(&s_pos[myci-1], 1);
    s_mem[r] = t;
    __syncthreads();
    int base = s_off[t];
    for(int a=1;a<icnt;++a){
        int key = s_mem[base+a];
        int b = a-1;
        while(b >= 0 && s_mem[base+b] > key){ s_mem[base+b+1] = s_mem[base+b]; --b; }
        s_mem[base+b+1] = key;
    }

    // ---- owner reductions in exact ascending order ----
    float smax = -1e30f, ssum = 0.f;
    for(int k=0;k<icnt;++k){
        int i = s_mem[base+k];
        smax = fmaxf(smax, s_sc[i]);
        ssum += s_sc[i];
    }
    float dref = -1e9f;
    for(int k=0;k<icnt;++k){
        int i = s_mem[base+k];
        float vv = (s_sc[i] == smax) ? s_dir[i] : -1e9f;
        dref = fmaxf(dref, vv);
    }
    float slt = 0.f, sle = 0.f;
    for(int k=0;k<icnt;++k){
        int i = s_mem[base+k];
        float diff = fabsf(s_dir[i] - dref);
        diff = (diff > PI_F) ? (TWO_PI_F - diff) : diff;
        if(diff > HALF_PI_F) slt += s_sc[i]; else sle += s_sc[i];
    }
    s_smax[t] = smax;
    s_ssum[t] = ssum;
    s_dref[t] = dref;
    s_keep[t] = (slt <= sle) ? 1 : 0;
    __syncthreads();

    // ---- per-box: flip, dir2, sn, weighted values (trig once per box) ----
    {
        int ow = myci - 1;
        float drefb = s_dref[ow];
        float diff = fabsf(dir - drefb);
        diff = (diff > PI_F) ? (TWO_PI_F - diff) : diff;
        bool gt = diff > HALF_PI_F;
        bool keep = s_keep[ow] != 0;
        bool flip = keep ? gt : !gt;
        float d2 = limit_period_f(dir + (flip ? PI_F : 0.f));
        float sn = sc / s_ssum[ow];
        s_val[0][t] = sinf(d2)*sn;
        s_val[1][t] = cosf(d2)*sn;
        s_val[2][t] = b0*sn;
        s_val[3][t] = b1*sn;
        s_val[4][t] = b2*sn;
        s_val[5][t] = b3*sn;
        s_val[6][t] = b4*sn;
        s_val[7][t] = b5*sn;
    }
    __syncthreads();

    // ---- owner weighted sums (ascending member order) ----
    float ssin=0.f, scos=0.f;
    float cd[6] = {0.f,0.f,0.f,0.f,0.f,0.f};
    for(int k=0;k<icnt;++k){
        int i = s_mem[base+k];
        ssin  += s_val[0][i];
        scos  += s_val[1][i];
        cd[0] += s_val[2][i];
        cd[1] += s_val[3][i];
        cd[2] += s_val[4][i];
        cd[3] += s_val[5][i];
        cd[4] += s_val[6][i];
        cd[5] += s_val[7][i];
    }
    float theta = atan2f(ssin, scos);

    // ---- epilogue ----
    bool valid = icnt > 0;
    float bf[7];
    #pragma unroll
    for(int d=0;d<6;++d) bf[d] = valid ? cd[d] : 0.f;
    bf[6] = valid ? theta : 0.f;
    {
        float cth=cosf(bf[6]), sth=sinf(bf[6]);
        const float tx[4]={0.5f,0.5f,-0.5f,-0.5f};
        const float ty[4]={0.5f,-0.5f,-0.5f,0.5f};
        bool inb = true;
        #pragma unroll
        for(int k=0;k<4;++k){
            float pxl = tx[k]*bf[5], pyl = ty[k]*bf[4];
            float gx = pxl*cth - pyl*sth + bf[0];
            float gy = pxl*sth + pyl*cth + bf[1];
            inb = inb && (gx > -140.8f) && (gx < 140.8f) && (gy > -40.0f) && (gy < 40.0f);
        }
        valid = valid && inb;
    }
    if(!valid){
        #pragma unroll
        for(int d=0;d<7;++d) bf[d]=0.f;
    }
    float sf = valid ? s_smax[t] : 0.f;
    int fh = *fhp, fw = *fwp;
    float ghf = (float)((40.0 - (-40.0)) / (double)fh);
    float gwf = (float)((140.8 - (-140.8)) / (double)fw);
    float gcx = (bf[0] + 140.8f) / gwf;
    float gcy = (bf[1] + 40.0f) / ghf;
    float gox = bf[5]*0.5f / gwf;
    float goy = bf[4]*0.5f / ghf + 1.0f;
    float xmin = fmaxf(gcx - gox, 0.f);
    float xmax = fminf(gcx + gox, (float)fw - 1.0f);
    float ymin = fmaxf(gcy - goy, 0.f);
    float ymax = fminf(gcy + goy, (float)fh - 1.0f);
    int r0 = (int)xmin, r1 = (int)xmax, r2 = (int)ymin, r3 = (int)ymax;
    if(!valid){ r0=0; r1=0; r2=0; r3=0; }
    #pragma unroll
    for(int d=0;d<7;++d) out[t*7+d] = bf[d];
    out[N*7 + t] = sf;
    out[N*8 + t] = valid ? 1.f : 0.f;
    out[N*9 + t*4 + 0] = (float)r0;
    out[N*9 + t*4 + 1] = (float)r1;
    out[N*9 + t*4 + 2] = (float)r2;
    out[N*9 + t*4 + 3] = (float)r3;
}

extern "C" void kernel_launch(void* const* d_in, const int* in_sizes, int n_in,
                              void* d_out, int out_size, void* d_ws, size_t ws_size,
                              hipStream_t stream) {
    const float* boxes  = (const float*)d_in[0];
    const float* scores = (const float*)d_in[1];
    const int*   fhp    = (const int*)d_in[2];
    const int*   fwp    = (const int*)d_in[3];
    float* out = (float*)d_out;
    ull* adj = (ull*)d_ws;               // 512*8*8 = 32768 bytes

    iou_kernel<<<N, 512, 0, stream>>>(boxes, adj);
    cluster_fuse_kernel<<<1, 512, 0, stream>>>(boxes, scores, adj, fhp, fwp, out);
}